// Round 6
// baseline (1349.648 us; speedup 1.0000x reference)
//
#include <hip/hip_runtime.h>
#include <math.h>

// KDC Lindblad propagator — real-basis reduction + fp64 MFMA.
// f64 16x16x4 C/D layout (HW-probed round 4): col=lane&15, row=(lane>>4)+4*reg.
// Pipeline: X = (tau/16) T; W = Taylor12(X) via PS; U = W^16; V = U^32;
// meet-in-middle chains; 14 dgemms total.
// dgemm (round 6): 256 thr / 4 waves; wave-tile 64x64 (4x4 MFMA accs),
// k-split-4 across waves within KT=64; 0.5 ds_read per MFMA (was 1.0);
// single LDS buffer (67584 B, known-good) + register prefetch;
// epilogue: 4-phase LDS k-reduction + cooperative coalesced store.

#define DS 1024
#define MATD ((size_t)DS * DS * sizeof(double))
#define PA 66   // LDS row pad: 16B-aligned rows, operand reads at bank floor

typedef double v4d __attribute__((ext_vector_type(4)));

__device__ inline double Qel(int i, int j) {
    if (i == j + 1) return sqrt((double)i) * 0.70710678118654752440;
    if (j == i + 1) return sqrt((double)j) * 0.70710678118654752440;
    return 0.0;
}

__device__ inline void fill_H(double* Hs, int tid) {
    const double CM2EV = 0.00012398419;
    const double E_S1 = 3.995, E_S2 = 4.9183;
    const double om6a = 596.0 * CM2EV, om10a = 919.0 * CM2EV;
    const double kapA = -0.0964, kapB = 0.1193, lam = 0.1825, gam = -0.018;
    for (int h = tid; h < 1024; h += 256) {
        int r = h >> 5, c = h & 31;
        int e = r >> 4, v6 = (r >> 2) & 3, v10 = r & 3;
        int e2 = c >> 4, w6 = (c >> 2) & 3, w10 = c & 3;
        double val = 0.0;
        if (r == c) val += (e ? E_S2 : E_S1) + om6a * v6 + om10a * v10;
        if (e == e2 && v10 == w10) val += (e ? kapB : kapA) * Qel(v6, w6);
        if (e != e2 && v6 == w6) {
            double q2 = 0.0;
            #pragma unroll
            for (int m = 0; m < 4; ++m) q2 += Qel(v10, m) * Qel(m, w10);
            val += lam * Qel(v10, w10) + gam * q2;
        }
        Hs[h] = val;
    }
}

// --------------------------------------------------------- build X ----------
__global__ __launch_bounds__(256)
void build_X(const float* __restrict__ logg, double* __restrict__ X)
{
    __shared__ double Hs[1024];
    int tid = threadIdx.x;
    fill_H(Hs, tid);
    __syncthreads();
    double g = exp((double)logg[0]);
    const double sc = (1.0 / 0.6582119569) / 16.0;   // (DT/HBAR)/2^4
    int idx = blockIdx.x * 256 + tid;
    int r = idx >> 10, c = idx & 1023;
    int i = r >> 5, j = r & 31;
    int k = c >> 5, l = c & 31;
    double t = 0.0;
    if (k <= l) {                  // R basis
        if (i <= j) {              // R row: dissipator only
            if (i < 16 && j < 16) {
                int p = i + 16, q = j + 16;
                if ((p == k && q == l) || (p == l && q == k)) t += g;
            }
            if (i == k && j == l) t -= 0.5 * g * ((i >= 16) + (j >= 16));
        } else {                   // A row: [H,R][i,j]
            if (j == l) t += Hs[i * 32 + k];
            if (k != l && j == k) t += Hs[i * 32 + l];
            if (i == k) t -= Hs[l * 32 + j];
            if (k != l && i == l) t -= Hs[k * 32 + j];
        }
    } else {                       // A basis (k>l)
        if (i <= j) {              // R row: -[H,A][i,j]
            double ha = 0.0;
            if (j == l) ha += Hs[i * 32 + k];
            if (j == k) ha -= Hs[i * 32 + l];
            if (i == k) ha -= Hs[l * 32 + j];
            if (i == l) ha += Hs[k * 32 + j];
            t -= ha;
        } else {                   // A row: dissipator
            if (i < 16 && j < 16 && (i + 16 == k) && (j + 16 == l)) t += g;
            if (i == k && j == l) t -= 0.5 * g * ((i >= 16) + (j >= 16));
        }
    }
    X[idx] = t * sc;
}

// --------------------------------------------------------- combo5 -----------
__global__ __launch_bounds__(256)
void combo5(const double* __restrict__ X, const double* __restrict__ X2,
            const double* __restrict__ X3, const double* __restrict__ X4,
            double* __restrict__ O,
            double c8, double c9, double c10, double c11, double c12)
{
    int idx = blockIdx.x * 256 + threadIdx.x;
    int r = idx >> 10, c = idx & 1023;
    double v = c9 * X[idx] + c10 * X2[idx] + c11 * X3[idx] + c12 * X4[idx];
    if (r == c) v += c8;
    O[idx] = v;
}

// --------------------------------------------------------- dgemm (MFMA f64) -
// D = A*B + d0*I + e1*E1 + e2*E2 + e3*E3 (E* may be null).
__global__ __launch_bounds__(256, 1)
void dgemm(const double* __restrict__ A, const double* __restrict__ B,
           double* __restrict__ D, double d0,
           const double* __restrict__ E1, double e1,
           const double* __restrict__ E2, double e2,
           const double* __restrict__ E3, double e3)
{
    __shared__ double As[64 * PA];   // [row][k]
    __shared__ double Bs[64 * PA];   // [k][col]
    const int tid = threadIdx.x;
    const int bm = blockIdx.x << 6, bn = blockIdx.y << 6;
    const int w = tid >> 6;          // wave = k-group (k-split-4)
    const int lane = tid & 63;
    const int lr = lane & 15, lk = lane >> 4;   // lr: A-row/B-col; lk: k-quad

    v4d acc[4][4];
    #pragma unroll
    for (int si = 0; si < 4; ++si)
        #pragma unroll
        for (int sj = 0; sj < 4; ++sj) acc[si][sj] = (v4d){0., 0., 0., 0.};

    // staging: thread covers rows {ra, ra+32} x 8 consecutive k (A) / cols (B)
    const int ra = tid >> 3, cs = (tid & 7) << 3;
    double va[16], vb[16];

    #pragma unroll
    for (int u = 0; u < 8; ++u) {
        va[u]     = A[(size_t)(bm + ra) * DS + cs + u];
        va[8 + u] = A[(size_t)(bm + ra + 32) * DS + cs + u];
        vb[u]     = B[(size_t)ra * DS + bn + cs + u];
        vb[8 + u] = B[(size_t)(ra + 32) * DS + bn + cs + u];
    }

    for (int kt = 0; kt < DS; kt += 64) {
        #pragma unroll
        for (int u = 0; u < 8; ++u) {
            As[ra * PA + cs + u]        = va[u];
            As[(ra + 32) * PA + cs + u] = va[8 + u];
            Bs[ra * PA + cs + u]        = vb[u];
            Bs[(ra + 32) * PA + cs + u] = vb[8 + u];
        }
        __syncthreads();
        if (kt + 64 < DS) {
            #pragma unroll
            for (int u = 0; u < 8; ++u) {
                va[u]     = A[(size_t)(bm + ra) * DS + kt + 64 + cs + u];
                va[8 + u] = A[(size_t)(bm + ra + 32) * DS + kt + 64 + cs + u];
                vb[u]     = B[(size_t)(kt + 64 + ra) * DS + bn + cs + u];
                vb[8 + u] = B[(size_t)(kt + 64 + ra + 32) * DS + bn + cs + u];
            }
        }
        #pragma unroll
        for (int s = 0; s < 4; ++s) {
            const int k = (w << 4) + (s << 2) + lk;
            double a[4], b[4];
            #pragma unroll
            for (int si = 0; si < 4; ++si) a[si] = As[(16 * si + lr) * PA + k];
            #pragma unroll
            for (int sj = 0; sj < 4; ++sj) b[sj] = Bs[k * PA + 16 * sj + lr];
            #pragma unroll
            for (int si = 0; si < 4; ++si)
                #pragma unroll
                for (int sj = 0; sj < 4; ++sj)
                    acc[si][sj] = __builtin_amdgcn_mfma_f64_16x16x4f64(
                        a[si], b[sj], acc[si][sj], 0, 0, 0);
        }
        __syncthreads();
    }

    // ---- k-split reduction through LDS (4 phases) ----
    double* red = As;   // 64x64 doubles
    #pragma unroll
    for (int ph = 3; ph >= 0; --ph) {
        if (w == ph) {
            #pragma unroll
            for (int si = 0; si < 4; ++si)
                #pragma unroll
                for (int sj = 0; sj < 4; ++sj)
                    #pragma unroll
                    for (int r = 0; r < 4; ++r) {
                        int off = (16 * si + lk + 4 * r) * 64 + 16 * sj + lr;
                        if (ph == 3) red[off] = acc[si][sj][r];
                        else         red[off] += acc[si][sj][r];
                    }
        }
        __syncthreads();
    }

    // ---- cooperative coalesced epilogue+store: 16 doubles/thread ----
    #pragma unroll
    for (int u = 0; u < 16; ++u) {
        int idx = (tid << 4) + u;
        int row = bm + (idx >> 6), col = bn + (idx & 63);
        double v = red[idx];
        size_t o = (size_t)row * DS + col;
        if (row == col) v += d0;
        if (E1) v += e1 * E1[o];
        if (E2) v += e2 * E2[o];
        if (E3) v += e3 * E3[o];
        D[o] = v;
    }
}

// --------------------------------------------------------- transpose --------
__global__ __launch_bounds__(256)
void transposeK(const double* __restrict__ M, double* __restrict__ MT)
{
    __shared__ double t[32][33];
    int bx = blockIdx.x << 5, by = blockIdx.y << 5;
    int x = threadIdx.x & 31, y = threadIdx.x >> 5;
    #pragma unroll
    for (int dy = 0; dy < 32; dy += 8)
        t[y + dy][x] = M[(size_t)(by + y + dy) * DS + bx + x];
    __syncthreads();
    #pragma unroll
    for (int dy = 0; dy < 32; dy += 8)
        MT[(size_t)(bx + y + dy) * DS + by + x] = t[x][y + dy];
}

// --------------------------------------------------------- chains -----------
__global__ __launch_bounds__(256)
void init_chains(double* __restrict__ Y, double* __restrict__ Z)
{
    int idx = blockIdx.x * 256 + threadIdx.x;
    if (idx < 2048) {
        int k = idx >> 10, i = idx & 1023;
        double v = 0.0;
        if (i % 33 == 0) {
            int a = i / 33;
            if ((a < 16) == (k == 0)) v = 1.0;
        }
        Y[idx] = v;
    } else if (idx < 3072) {
        int i = idx - 2048;
        Z[i] = (i == 528) ? 1.0 : 0.0;
    }
}

__global__ __launch_bounds__(256)
void chain_step(const double* __restrict__ UT, const double* __restrict__ V,
                const double* __restrict__ Yin, double* __restrict__ Yout,
                const double* __restrict__ Zin, double* __restrict__ Zout)
{
    int gw = blockIdx.x * 4 + (threadIdx.x >> 6);
    int lane = threadIdx.x & 63;
    if (gw < 1024) {
        const double* row = UT + (size_t)gw * DS;
        double s0 = 0.0, s1 = 0.0;
        for (int kk = lane; kk < DS; kk += 64) {
            double m = row[kk];
            s0 += m * Yin[kk];
            s1 += m * Yin[DS + kk];
        }
        #pragma unroll
        for (int off = 32; off; off >>= 1) {
            s0 += __shfl_down(s0, off);
            s1 += __shfl_down(s1, off);
        }
        if (lane == 0) { Yout[gw] = s0; Yout[DS + gw] = s1; }
    } else {
        int r = gw - 1024;
        const double* row = V + (size_t)r * DS;
        double s = 0.0;
        for (int kk = lane; kk < DS; kk += 64) s += row[kk] * Zin[kk];
        #pragma unroll
        for (int off = 32; off; off >>= 1) s += __shfl_down(s, off);
        if (lane == 0) Zout[r] = s;
    }
}

// --------------------------------------------------------- output -----------
__global__ __launch_bounds__(128)
void final_pops(const double* __restrict__ Y, const double* __restrict__ Z,
                float* __restrict__ out, int n)
{
    int t = blockIdx.x;
    int k = threadIdx.x >> 6, lane = threadIdx.x & 63;
    int a = t & 31, j = t >> 5;
    const double* y = Y + (size_t)a * 2048 + (size_t)k * 1024;
    const double* z = Z + (size_t)j * 1024;
    double s = 0.0;
    for (int i = lane; i < 1024; i += 64) s += y[i] * z[i];
    #pragma unroll
    for (int off = 32; off; off >>= 1) s += __shfl_down(s, off);
    if (lane == 0) {
        out[(size_t)(k + 1) * n + t] = (float)s;
        if (k == 0) out[t] = 0.0f;
    }
}

// --------------------------------------------------------- host -------------
extern "C" void kernel_launch(void* const* d_in, const int* in_sizes, int n_in,
                              void* d_out, int out_size, void* d_ws, size_t ws_size,
                              hipStream_t stream)
{
    const float* logg = (const float*)d_in[0];
    float* out = (float*)d_out;
    const int n = out_size / 3;
    (void)in_sizes; (void)n_in; (void)ws_size;

    char* ws = (char*)d_ws;
    double* b0 = (double*)(ws + 0 * MATD);
    double* b1 = (double*)(ws + 1 * MATD);
    double* b2 = (double*)(ws + 2 * MATD);
    double* b3 = (double*)(ws + 3 * MATD);
    double* b4 = (double*)(ws + 4 * MATD);
    double* b5 = (double*)(ws + 5 * MATD);
    double* b6 = (double*)(ws + 6 * MATD);
    double* Y  = (double*)(ws + 7 * MATD);   // 32 x 2 x 1024
    double* Z  = Y + 32 * 2048;              // 32 x 1024

    const double C2 = 1.0/2.0, C3 = 1.0/6.0;
    const double C4 = 1.0/24.0, C5 = 1.0/120.0, C6 = 1.0/720.0, C7 = 1.0/5040.0;
    const double C8 = 1.0/40320.0, C9 = 1.0/362880.0, C10 = 1.0/3628800.0,
                 C11 = 1.0/39916800.0, C12 = 1.0/479001600.0;

    dim3 g2(16, 16);
    const double* NUL = nullptr;
    build_X<<<4096, 256, 0, stream>>>(logg, b0);                       // X
    dgemm<<<g2, 256, 0, stream>>>(b0, b0, b1, 0., NUL,0., NUL,0., NUL,0.); // X2
    dgemm<<<g2, 256, 0, stream>>>(b1, b0, b2, 0., NUL,0., NUL,0., NUL,0.); // X3
    dgemm<<<g2, 256, 0, stream>>>(b1, b1, b3, 0., NUL,0., NUL,0., NUL,0.); // X4
    combo5<<<4096, 256, 0, stream>>>(b0, b1, b2, b3, b4, C8, C9, C10, C11, C12); // H1
    dgemm<<<g2, 256, 0, stream>>>(b4, b3, b5, C4, b0,C5, b1,C6, b2,C7); // H2=H1@X4+Q1
    dgemm<<<g2, 256, 0, stream>>>(b5, b3, b4, 1., b0,1., b1,C2, b2,C3); // W =H2@X4+Q0
    dgemm<<<g2, 256, 0, stream>>>(b4, b4, b5, 0., NUL,0., NUL,0., NUL,0.); // W^2
    dgemm<<<g2, 256, 0, stream>>>(b5, b5, b6, 0., NUL,0., NUL,0., NUL,0.); // W^4
    dgemm<<<g2, 256, 0, stream>>>(b6, b6, b0, 0., NUL,0., NUL,0., NUL,0.); // W^8
    dgemm<<<g2, 256, 0, stream>>>(b0, b0, b3, 0., NUL,0., NUL,0., NUL,0.); // U=W^16
    dgemm<<<g2, 256, 0, stream>>>(b3, b3, b1, 0., NUL,0., NUL,0., NUL,0.); // U^2
    dgemm<<<g2, 256, 0, stream>>>(b1, b1, b2, 0., NUL,0., NUL,0., NUL,0.); // U^4
    dgemm<<<g2, 256, 0, stream>>>(b2, b2, b5, 0., NUL,0., NUL,0., NUL,0.); // U^8
    dgemm<<<g2, 256, 0, stream>>>(b5, b5, b6, 0., NUL,0., NUL,0., NUL,0.); // U^16
    dgemm<<<g2, 256, 0, stream>>>(b6, b6, b1, 0., NUL,0., NUL,0., NUL,0.); // V=U^32
    transposeK<<<dim3(32, 32), 256, 0, stream>>>(b3, b0);              // UT
    init_chains<<<12, 256, 0, stream>>>(Y, Z);
    for (int a = 1; a < 32; ++a)
        chain_step<<<512, 256, 0, stream>>>(b0, b1,
            Y + (size_t)(a - 1) * 2048, Y + (size_t)a * 2048,
            Z + (size_t)(a - 1) * 1024, Z + (size_t)a * 1024);
    final_pops<<<n, 128, 0, stream>>>(Y, Z, out, n);
}

// Round 7
// 919.174 us; speedup vs baseline: 1.4683x; 1.4683x over previous
//
#include <hip/hip_runtime.h>
#include <math.h>

// KDC Lindblad propagator — real-basis reduction + fp64 MFMA + sparse Horner.
// f64 16x16x4 C/D layout (HW-probed round 4): col=lane&15, row=(lane>>4)+4*reg.
//
// Round 7: Taylor phase = 16 sparse T-applies (Horner, ~16 source rows per
// output row, coefficient maps derived from the validated build_X), so only
// the 8 squarings (W->U=W^8: 3, V=U^32: 5) are dense 1024^3 GEMMs.
// dgemm reverted verbatim to round-5 (67 us known-good; round-6 4x4-acc
// variant regressed to 94 us: 1 wave/SIMD has no stall coverage).

#define DS 1024
#define MATD ((size_t)DS * DS * sizeof(double))
#define PA 66   // LDS pad

typedef double v4d __attribute__((ext_vector_type(4)));

__device__ inline double Qel(int i, int j) {
    if (i == j + 1) return sqrt((double)i) * 0.70710678118654752440;
    if (j == i + 1) return sqrt((double)j) * 0.70710678118654752440;
    return 0.0;
}

__device__ inline void fill_H(double* Hs, int tid) {
    const double CM2EV = 0.00012398419;
    const double E_S1 = 3.995, E_S2 = 4.9183;
    const double om6a = 596.0 * CM2EV, om10a = 919.0 * CM2EV;
    const double kapA = -0.0964, kapB = 0.1193, lam = 0.1825, gam = -0.018;
    for (int h = tid; h < 1024; h += 256) {
        int r = h >> 5, c = h & 31;
        int e = r >> 4, v6 = (r >> 2) & 3, v10 = r & 3;
        int e2 = c >> 4, w6 = (c >> 2) & 3, w10 = c & 3;
        double val = 0.0;
        if (r == c) val += (e ? E_S2 : E_S1) + om6a * v6 + om10a * v10;
        if (e == e2 && v10 == w10) val += (e ? kapB : kapA) * Qel(v6, w6);
        if (e != e2 && v6 == w6) {
            double q2 = 0.0;
            #pragma unroll
            for (int m = 0; m < 4; ++m) q2 += Qel(v10, m) * Qel(m, w10);
            val += lam * Qel(v10, w10) + gam * q2;
        }
        Hs[h] = val;
    }
}

// --------------------------------------------------------- identity ---------
__global__ __launch_bounds__(256)
void set_identity(double* __restrict__ M)
{
    int idx = blockIdx.x * 256 + threadIdx.x;
    M[idx] = ((idx >> 10) == (idx & 1023)) ? 1.0 : 0.0;
}

// --------------------------------------------------------- sparse T-apply ---
// O = I + sck * (T @ M), sck = (DT/HBAR)/8 / k  (Horner step).
// One block per output row p=(i,j); ~16 active source rows, block-uniform
// loops; threads cover the 1024 row elements (4 each, stride 256).
// Coefficient maps verified against the validated build_X:
//  R-out (i<=j): sum_m H[i,m]*(-A[m,j]) + sum_m H[m,j]*A[i,m]
//                + g*[i,j<16]*u[P(i+16,j+16)] - g/2((i>=16)+(j>=16))*u[p]
//  A-out (i>j):  sum_m H[i,m]*R[m,j] - sum_m H[m,j]*R[i,m]
//                + g*[i,j<16]*u[P(i+16,j+16)] - g/2((i>=16)+(j>=16))*u[p]
//  R[a,b]=u[P(min,max)]; A[a,b]=+u[P(a,b)] a>b, -u[P(b,a)] a<b, 0 diag.
__global__ __launch_bounds__(256)
void apply_T(const float* __restrict__ logg, const double* __restrict__ M,
             double* __restrict__ O, double invk)
{
    __shared__ double Hs[1024];
    const int tid = threadIdx.x;
    fill_H(Hs, tid);
    __syncthreads();
    const double g = exp((double)logg[0]);
    const double sck = ((1.0 / 0.6582119569) / 8.0) * invk;
    const int p = blockIdx.x;
    const int i = p >> 5, j = p & 31;

    double a0 = 0.0, a1 = 0.0, a2 = 0.0, a3 = 0.0;
    const int e = tid;

#define ADDROW(q, wgt) { const double* r_ = M + (size_t)(q) * DS; double w_ = (wgt); \
    a0 += w_ * r_[e]; a1 += w_ * r_[e + 256];                                        \
    a2 += w_ * r_[e + 512]; a3 += w_ * r_[e + 768]; }

    if (i <= j) {   // R-output row
        for (int m = 0; m < 32; ++m) {
            double c = Hs[i * 32 + m];
            if (c != 0.0 && m != j) {
                if (m > j) ADDROW(m * 32 + j, -c)
                else       ADDROW(j * 32 + m,  c)
            }
        }
        for (int m = 0; m < 32; ++m) {
            double c = Hs[m * 32 + j];
            if (c != 0.0 && m != i) {
                if (i > m) ADDROW(i * 32 + m,  c)
                else       ADDROW(m * 32 + i, -c)
            }
        }
        if (i < 16 && j < 16) ADDROW((i + 16) * 32 + (j + 16), g)
        if (i >= 16 || j >= 16)
            ADDROW(p, -0.5 * g * (double)((i >= 16) + (j >= 16)))
    } else {        // A-output row
        for (int m = 0; m < 32; ++m) {
            double c = Hs[i * 32 + m];
            if (c != 0.0) {
                int lo = m < j ? m : j, hi = m < j ? j : m;
                ADDROW(lo * 32 + hi, c)
            }
        }
        for (int m = 0; m < 32; ++m) {
            double c = Hs[m * 32 + j];
            if (c != 0.0) {
                int lo = m < i ? m : i, hi = m < i ? i : m;
                ADDROW(lo * 32 + hi, -c)
            }
        }
        if (i < 16 && j < 16) ADDROW((i + 16) * 32 + (j + 16), g)
        ADDROW(p, -0.5 * g * (double)((i >= 16) + (j >= 16)))
    }
#undef ADDROW

    size_t base = (size_t)p * DS;
    O[base + e]       = sck * a0 + ((p == e)       ? 1.0 : 0.0);
    O[base + e + 256] = sck * a1 + ((p == e + 256) ? 1.0 : 0.0);
    O[base + e + 512] = sck * a2 + ((p == e + 512) ? 1.0 : 0.0);
    O[base + e + 768] = sck * a3 + ((p == e + 768) ? 1.0 : 0.0);
}

// --------------------------------------------------------- dgemm (MFMA f64) -
// ROUND-5 VERBATIM (67 us known-good). D = A*B + d0*I + e*E terms.
// 64x64 tile, 512 threads (8 waves): 4 output-pairs x 2 k-groups; KT=64.
__global__ __launch_bounds__(512)
void dgemm(const double* __restrict__ A, const double* __restrict__ B,
           double* __restrict__ D, double d0,
           const double* __restrict__ E1, double e1,
           const double* __restrict__ E2, double e2,
           const double* __restrict__ E3, double e3)
{
    __shared__ double As[64 * PA];   // [row][k]
    __shared__ double Bs[64 * PA];   // [k][col]
    const int tid = threadIdx.x;
    const int bm = blockIdx.x << 6, bn = blockIdx.y << 6;
    const int w = tid >> 6, lane = tid & 63;
    const int lr = lane & 15, lk = lane >> 4;
    const int p = w & 3, kg = w >> 2;
    const int wr = (p >> 1) << 5, wc = (p & 1) << 5;

    v4d acc00 = {0.,0.,0.,0.}, acc01 = {0.,0.,0.,0.};
    v4d acc10 = {0.,0.,0.,0.}, acc11 = {0.,0.,0.,0.};

    const int ra = tid >> 3;
    const int cs = (tid & 7) << 3;
    const double* gA = A + (size_t)(bm + ra) * DS + cs;
    const double* gB = B + (size_t)ra * DS + bn + cs;

    double va[8], vb[8];
    #pragma unroll
    for (int u = 0; u < 8; ++u) va[u] = gA[u];
    #pragma unroll
    for (int u = 0; u < 8; ++u) vb[u] = gB[u];

    for (int kt = 0; kt < DS; kt += 64) {
        #pragma unroll
        for (int u = 0; u < 8; ++u) As[ra * PA + cs + u] = va[u];
        #pragma unroll
        for (int u = 0; u < 8; ++u) Bs[ra * PA + cs + u] = vb[u];
        __syncthreads();
        if (kt + 64 < DS) {
            #pragma unroll
            for (int u = 0; u < 8; ++u) va[u] = gA[kt + 64 + u];
            #pragma unroll
            for (int u = 0; u < 8; ++u) vb[u] = gB[(size_t)(kt + 64) * DS + u];
        }
        #pragma unroll
        for (int s = 0; s < 8; ++s) {
            int k = (((s << 1) | kg) << 2) + lk;
            double a0 = As[(wr + lr) * PA + k];
            double a1 = As[(wr + 16 + lr) * PA + k];
            double b0 = Bs[k * PA + wc + lr];
            double b1 = Bs[k * PA + wc + 16 + lr];
            acc00 = __builtin_amdgcn_mfma_f64_16x16x4f64(a0, b0, acc00, 0, 0, 0);
            acc01 = __builtin_amdgcn_mfma_f64_16x16x4f64(a0, b1, acc01, 0, 0, 0);
            acc10 = __builtin_amdgcn_mfma_f64_16x16x4f64(a1, b0, acc10, 0, 0, 0);
            acc11 = __builtin_amdgcn_mfma_f64_16x16x4f64(a1, b1, acc11, 0, 0, 0);
        }
        __syncthreads();
    }

    double* red = As;
    if (kg == 1) {
        #pragma unroll
        for (int si = 0; si < 2; ++si)
            #pragma unroll
            for (int sj = 0; sj < 2; ++sj) {
                v4d acc = (si == 0) ? (sj == 0 ? acc00 : acc01)
                                    : (sj == 0 ? acc10 : acc11);
                #pragma unroll
                for (int r = 0; r < 4; ++r)
                    red[(p * 16 + si * 8 + sj * 4 + r) * 64 + lane] = acc[r];
            }
    }
    __syncthreads();
    if (kg == 0) {
        #pragma unroll
        for (int si = 0; si < 2; ++si)
            #pragma unroll
            for (int sj = 0; sj < 2; ++sj) {
                v4d acc = (si == 0) ? (sj == 0 ? acc00 : acc01)
                                    : (sj == 0 ? acc10 : acc11);
                int col = bn + wc + (sj << 4) + lr;
                #pragma unroll
                for (int r = 0; r < 4; ++r) {
                    int row = bm + wr + (si << 4) + lk + (r << 2);
                    double v = acc[r] + red[(p * 16 + si * 8 + sj * 4 + r) * 64 + lane];
                    size_t o = (size_t)row * DS + col;
                    if (row == col) v += d0;
                    if (E1) v += e1 * E1[o];
                    if (E2) v += e2 * E2[o];
                    if (E3) v += e3 * E3[o];
                    D[o] = v;
                }
            }
    }
}

// --------------------------------------------------------- transpose --------
__global__ __launch_bounds__(256)
void transposeK(const double* __restrict__ M, double* __restrict__ MT)
{
    __shared__ double t[32][33];
    int bx = blockIdx.x << 5, by = blockIdx.y << 5;
    int x = threadIdx.x & 31, y = threadIdx.x >> 5;
    #pragma unroll
    for (int dy = 0; dy < 32; dy += 8)
        t[y + dy][x] = M[(size_t)(by + y + dy) * DS + bx + x];
    __syncthreads();
    #pragma unroll
    for (int dy = 0; dy < 32; dy += 8)
        MT[(size_t)(bx + y + dy) * DS + by + x] = t[x][y + dy];
}

// --------------------------------------------------------- chains -----------
__global__ __launch_bounds__(256)
void init_chains(double* __restrict__ Y, double* __restrict__ Z)
{
    int idx = blockIdx.x * 256 + threadIdx.x;
    if (idx < 2048) {
        int k = idx >> 10, i = idx & 1023;
        double v = 0.0;
        if (i % 33 == 0) {
            int a = i / 33;
            if ((a < 16) == (k == 0)) v = 1.0;
        }
        Y[idx] = v;
    } else if (idx < 3072) {
        int i = idx - 2048;
        Z[i] = (i == 528) ? 1.0 : 0.0;
    }
}

__global__ __launch_bounds__(256)
void chain_step(const double* __restrict__ UT, const double* __restrict__ V,
                const double* __restrict__ Yin, double* __restrict__ Yout,
                const double* __restrict__ Zin, double* __restrict__ Zout)
{
    int gw = blockIdx.x * 4 + (threadIdx.x >> 6);
    int lane = threadIdx.x & 63;
    if (gw < 1024) {
        const double* row = UT + (size_t)gw * DS;
        double s0 = 0.0, s1 = 0.0;
        for (int kk = lane; kk < DS; kk += 64) {
            double m = row[kk];
            s0 += m * Yin[kk];
            s1 += m * Yin[DS + kk];
        }
        #pragma unroll
        for (int off = 32; off; off >>= 1) {
            s0 += __shfl_down(s0, off);
            s1 += __shfl_down(s1, off);
        }
        if (lane == 0) { Yout[gw] = s0; Yout[DS + gw] = s1; }
    } else {
        int r = gw - 1024;
        const double* row = V + (size_t)r * DS;
        double s = 0.0;
        for (int kk = lane; kk < DS; kk += 64) s += row[kk] * Zin[kk];
        #pragma unroll
        for (int off = 32; off; off >>= 1) s += __shfl_down(s, off);
        if (lane == 0) Zout[r] = s;
    }
}

// --------------------------------------------------------- output -----------
__global__ __launch_bounds__(128)
void final_pops(const double* __restrict__ Y, const double* __restrict__ Z,
                float* __restrict__ out, int n)
{
    int t = blockIdx.x;
    int k = threadIdx.x >> 6, lane = threadIdx.x & 63;
    int a = t & 31, j = t >> 5;
    const double* y = Y + (size_t)a * 2048 + (size_t)k * 1024;
    const double* z = Z + (size_t)j * 1024;
    double s = 0.0;
    for (int i = lane; i < 1024; i += 64) s += y[i] * z[i];
    #pragma unroll
    for (int off = 32; off; off >>= 1) s += __shfl_down(s, off);
    if (lane == 0) {
        out[(size_t)(k + 1) * n + t] = (float)s;
        if (k == 0) out[t] = 0.0f;
    }
}

// --------------------------------------------------------- host -------------
extern "C" void kernel_launch(void* const* d_in, const int* in_sizes, int n_in,
                              void* d_out, int out_size, void* d_ws, size_t ws_size,
                              hipStream_t stream)
{
    const float* logg = (const float*)d_in[0];
    float* out = (float*)d_out;
    const int n = out_size / 3;
    (void)in_sizes; (void)n_in; (void)ws_size;

    char* ws = (char*)d_ws;
    double* b0 = (double*)(ws + 0 * MATD);
    double* b1 = (double*)(ws + 1 * MATD);
    double* b2 = (double*)(ws + 2 * MATD);
    double* b3 = (double*)(ws + 3 * MATD);
    double* Y  = (double*)(ws + 4 * MATD);   // 32 x 2 x 1024
    double* Z  = Y + 32 * 2048;              // 32 x 1024

    dim3 g2(16, 16);
    const double* NUL = nullptr;

    // ---- W = Taylor16(tau*T/8) via sparse Horner: G = I + (X G)/k ----
    set_identity<<<4096, 256, 0, stream>>>(b0);
    double* src = b0; double* dst = b1;
    for (int k = 16; k >= 1; --k) {
        apply_T<<<1024, 256, 0, stream>>>(logg, src, dst, 1.0 / (double)k);
        double* t = src; src = dst; dst = t;
    }
    // 16 applies (even) -> W in b0

    // ---- U = W^8 (3 sq), V = U^32 (5 sq) ----
    dgemm<<<g2, 512, 0, stream>>>(b0, b0, b1, 0., NUL,0., NUL,0., NUL,0.); // W^2
    dgemm<<<g2, 512, 0, stream>>>(b1, b1, b2, 0., NUL,0., NUL,0., NUL,0.); // W^4
    dgemm<<<g2, 512, 0, stream>>>(b2, b2, b3, 0., NUL,0., NUL,0., NUL,0.); // U=W^8
    dgemm<<<g2, 512, 0, stream>>>(b3, b3, b1, 0., NUL,0., NUL,0., NUL,0.); // U^2
    dgemm<<<g2, 512, 0, stream>>>(b1, b1, b2, 0., NUL,0., NUL,0., NUL,0.); // U^4
    dgemm<<<g2, 512, 0, stream>>>(b2, b2, b1, 0., NUL,0., NUL,0., NUL,0.); // U^8
    dgemm<<<g2, 512, 0, stream>>>(b1, b1, b2, 0., NUL,0., NUL,0., NUL,0.); // U^16
    dgemm<<<g2, 512, 0, stream>>>(b2, b2, b1, 0., NUL,0., NUL,0., NUL,0.); // V=U^32

    // ---- chains ----
    transposeK<<<dim3(32, 32), 256, 0, stream>>>(b3, b0);              // UT
    init_chains<<<12, 256, 0, stream>>>(Y, Z);
    for (int a = 1; a < 32; ++a)
        chain_step<<<512, 256, 0, stream>>>(b0, b1,
            Y + (size_t)(a - 1) * 2048, Y + (size_t)a * 2048,
            Z + (size_t)(a - 1) * 1024, Z + (size_t)a * 1024);
    final_pops<<<n, 128, 0, stream>>>(Y, Z, out, n);
}